// Round 2
// baseline (540.386 us; speedup 1.0000x reference)
//
#include <hip/hip_runtime.h>
#include <math.h>

typedef __attribute__((ext_vector_type(8))) short short8v;
typedef __attribute__((ext_vector_type(4))) float f32x4;

#define NB 64
#define CC 64
#define TT 300
#define VV 25
#define SS 3
#define TB 4
#define TBLK (TT/TB)    // 75
#define COLSF (TB*VV)   // 100

// ws float layout: [0:64] sum, [64:128] sumsq, [128:192] scale, [192:256] shift,
// [256:320] summed bias; byte offset 2048: A-hat fragments [s][nt][lane] short8 (6144 B)

static __device__ __forceinline__ short f2bf(float f){
    unsigned u = __float_as_uint(f);
    u += 0x7fff + ((u >> 16) & 1);
    return (short)(u >> 16);
}

__global__ void gcn_prep(const float* __restrict__ PA, const float* __restrict__ bc,
                         float* __restrict__ ws)
{
    __shared__ float inv[SS][VV];
    const int tid = threadIdx.x;   // 384 threads
    if (tid < SS*VV){
        int s = tid/VV, w = tid%VV;
        float sum = 0.f;
        for (int v=0; v<VV; ++v){ float p = PA[s*VV*VV + v*VV + w]; sum = fmaf(p,p,sum); }
        inv[s][w] = 1.f/(sqrtf(sum)+1e-4f);
    }
    if (tid < 256) ws[tid] = 0.f;
    if (tid >= 256 && tid < 320){ int o = tid-256; ws[tid] = bc[o]+bc[CC+o]+bc[2*CC+o]; }
    __syncthreads();
    {   // fragment-ready normalized adjacency, zeros for v>=25 / w>=25
        int s = tid/128, rem = tid%128, nt = rem/64, lane = rem%64;
        int w = nt*16 + (lane&15), g = lane>>4;
        short8v vals;
        #pragma unroll
        for (int j=0;j<8;++j){
            int v = 8*g + j;
            float f = (v<VV && w<VV) ? PA[s*VV*VV + v*VV + w]*inv[s][w] : 0.f;
            vals[j] = f2bf(f);
        }
        *(short8v*)((char*)ws + 2048 + (size_t)((s*2+nt)*64 + lane)*16) = vals;
    }
}

__global__ __launch_bounds__(256,4) void gcn_main_kernel(
    const float* __restrict__ x, const float* __restrict__ Wc,
    const float* __restrict__ ws, float* __restrict__ yout)
{
    __shared__ short xs[256][40];    // rows=(c*4+t), bf16, v padded to 40
    __shared__ short zsT[112][72];   // rows=(t*25+w) padded to 112, cols=c padded to 72

    const int tid = threadIdx.x;
    const int wv  = tid >> 6, lane = tid & 63;
    const int l15 = lane & 15, g = lane >> 4;
    const int n   = blockIdx.x / TBLK;
    const int t0  = (blockIdx.x % TBLK) * TB;
    float* stats  = (float*)ws;

    // zero junk K-columns 25..31 (avoid NaN*0 in MFMA); col 24 left to staging
    xs[tid][25] = 0;
    *(int*)&xs[tid][26] = 0;
    *(int2*)&xs[tid][28] = make_int2(0,0);

    // stage x tile -> xs bf16 (flat-coalesced float4 loads, b16 scatter writes)
    const float4* x4 = (const float4*)(x + (size_t)n*(CC*TT*VV) + (size_t)t0*VV);
    for (int i4 = tid; i4 < CC*COLSF/4; i4 += 256){    // 1600 float4
        int c = i4 / (COLSF/4);
        int j = i4 % (COLSF/4);
        float4 v4 = x4[c*(TT*VV/4) + j];
        float vals[4] = {v4.x, v4.y, v4.z, v4.w};
        int e = 4*j;
        #pragma unroll
        for (int k=0;k<4;++k){
            int ee = e+k;
            xs[c*TB + ee/VV][ee%VV] = f2bf(vals[k]);
        }
    }

    // A-hat fragments (stage-A B operand) from ws — wave-uniform-ish, L2 cached
    short8v afA[SS][2];
    const short8v* wsfrag = (const short8v*)((const char*)ws + 2048);
    #pragma unroll
    for (int s=0;s<SS;++s)
        #pragma unroll
        for (int nt=0;nt<2;++nt)
            afA[s][nt] = wsfrag[(s*2+nt)*64 + lane];

    // Wc fragments (stage-B A operand): o = 16*wv + l15, c = kt*32 + 8g + j
    short8v wcf[SS][2];
    #pragma unroll
    for (int s=0;s<SS;++s)
        #pragma unroll
        for (int kt=0;kt<2;++kt){
            const float* wp = Wc + ((size_t)s*CC + (16*wv + l15))*CC + kt*32 + 8*g;
            float4 w0 = *(const float4*)wp;
            float4 w1 = *(const float4*)(wp+4);
            short8v t;
            t[0]=f2bf(w0.x); t[1]=f2bf(w0.y); t[2]=f2bf(w0.z); t[3]=f2bf(w0.w);
            t[4]=f2bf(w1.x); t[5]=f2bf(w1.y); t[6]=f2bf(w1.z); t[7]=f2bf(w1.w);
            wcf[s][kt] = t;
        }

    __syncthreads();

    // hoisted x A-fragments: wave owns rows [64*wv, 64*wv+64)
    short8v axf[4];
    #pragma unroll
    for (int mt=0; mt<4; ++mt)
        axf[mt] = *(const short8v*)&xs[64*wv + 16*mt + l15][8*g];

    const f32x4 zf = {0.f,0.f,0.f,0.f};
    f32x4 yacc[7];
    #pragma unroll
    for (int nt=0; nt<7; ++nt) yacc[nt] = zf;

    for (int s=0; s<SS; ++s){
        // stage A: Z = X * A_hat[s]   (pure-register MFMA)
        f32x4 za[4][2];
        #pragma unroll
        for (int mt=0;mt<4;++mt)
            #pragma unroll
            for (int nt=0;nt<2;++nt)
                za[mt][nt] = __builtin_amdgcn_mfma_f32_16x16x32_bf16(axf[mt], afA[s][nt], zf, 0,0,0);

        __syncthreads();   // all waves done reading zsT of previous s
        // scatter Z -> zsT transposed (bf16): lane holds Z[c=16wv+4mt+g][t=r][w=nt*16+l15]
        #pragma unroll
        for (int mt=0;mt<4;++mt){
            int c = 16*wv + 4*mt + g;
            #pragma unroll
            for (int nt=0;nt<2;++nt){
                int w = nt*16 + l15;
                if (w < VV){
                    #pragma unroll
                    for (int r=0;r<4;++r)
                        zsT[r*VV + w][c] = f2bf(za[mt][nt][r]);
                }
            }
        }
        __syncthreads();

        // stage B: yacc += Wc[s] * Z   (K = c = 64, 2 k-tiles)
        #pragma unroll
        for (int kt=0;kt<2;++kt)
            #pragma unroll
            for (int nt=0;nt<7;++nt){
                short8v bz = *(const short8v*)&zsT[nt*16 + l15][kt*32 + 8*g];
                yacc[nt] = __builtin_amdgcn_mfma_f32_16x16x32_bf16(wcf[s][kt], bz, yacc[nt], 0,0,0);
            }
    }

    // epilogue: bias, store unnormalized y, channel stats
    const float* wsb = ws + 256;
    float s1[4] = {0,0,0,0}, s2[4] = {0,0,0,0};
    #pragma unroll
    for (int nt=0; nt<7; ++nt){
        int col = nt*16 + l15;
        if (col < COLSF){
            int t = col/VV, w = col%VV;
            #pragma unroll
            for (int r=0;r<4;++r){
                int o = 16*wv + 4*g + r;
                float v = yacc[nt][r] + wsb[o];
                yout[(((size_t)n*CC + o)*TT + t0 + t)*VV + w] = v;
                s1[r] += v;
                s2[r] = fmaf(v,v,s2[r]);
            }
        }
    }
    #pragma unroll
    for (int st=1; st<16; st<<=1){
        #pragma unroll
        for (int r=0;r<4;++r){
            s1[r] += __shfl_xor(s1[r], st);
            s2[r] += __shfl_xor(s2[r], st);
        }
    }
    if (l15 == 0){
        #pragma unroll
        for (int r=0;r<4;++r){
            int o = 16*wv + 4*g + r;
            atomicAdd(&stats[o], s1[r]);
            atomicAdd(&stats[CC + o], s2[r]);
        }
    }
}

__global__ void gcn_finalize_kernel(const float* __restrict__ gamma,
                                    const float* __restrict__ beta,
                                    float* __restrict__ ws)
{
    const int o = threadIdx.x;
    if (o < CC) {
        const float cnt = (float)(NB * TT * VV);   // 480000
        const float mean = ws[o] / cnt;
        const float var  = ws[64 + o] / cnt - mean * mean;
        const float sc   = gamma[o] * rsqrtf(var + 1e-5f);
        ws[128 + o] = sc;
        ws[192 + o] = beta[o] - mean * sc;
    }
}

__global__ __launch_bounds__(256) void gcn_bn_relu_kernel(
    const float* __restrict__ x, float* __restrict__ y,
    const float* __restrict__ ws)
{
    const int total4 = NB * CC * TT * VV / 4;   // 7,680,000
    const int per_c4 = TT * VV / 4;             // 1875
    for (int i = blockIdx.x * 256 + threadIdx.x; i < total4; i += gridDim.x * 256) {
        const int c = (i / per_c4) & (CC - 1);
        const float sc = ws[128 + c];
        const float sh = ws[192 + c];
        float4 yv = reinterpret_cast<float4*>(y)[i];
        float4 xv = reinterpret_cast<const float4*>(x)[i];
        float4 r;
        r.x = fmaxf(fmaf(yv.x, sc, sh) + xv.x, 0.f);
        r.y = fmaxf(fmaf(yv.y, sc, sh) + xv.y, 0.f);
        r.z = fmaxf(fmaf(yv.z, sc, sh) + xv.z, 0.f);
        r.w = fmaxf(fmaf(yv.w, sc, sh) + xv.w, 0.f);
        reinterpret_cast<float4*>(y)[i] = r;
    }
}

extern "C" void kernel_launch(void* const* d_in, const int* in_sizes, int n_in,
                              void* d_out, int out_size, void* d_ws, size_t ws_size,
                              hipStream_t stream)
{
    const float* x     = (const float*)d_in[0];
    const float* PA    = (const float*)d_in[1];
    const float* Wc    = (const float*)d_in[2];
    const float* bc    = (const float*)d_in[3];
    const float* gamma = (const float*)d_in[4];
    const float* beta  = (const float*)d_in[5];
    float* out = (float*)d_out;
    float* ws  = (float*)d_ws;

    gcn_prep<<<1, 384, 0, stream>>>(PA, bc, ws);
    gcn_main_kernel<<<NB * TBLK, 256, 0, stream>>>(x, Wc, ws, out);
    gcn_finalize_kernel<<<1, 64, 0, stream>>>(gamma, beta, ws);
    gcn_bn_relu_kernel<<<2048, 256, 0, stream>>>(x, out, ws);
}

// Round 3
// 200.411 us; speedup vs baseline: 2.6964x; 2.6964x over previous
//
#include <hip/hip_runtime.h>
#include <math.h>

typedef __attribute__((ext_vector_type(8))) short short8v;
typedef __attribute__((ext_vector_type(4))) float f32x4;

#define NB 64
#define CC 64
#define TT 300
#define VV 25
#define SS 3
#define TB 4
#define TBLK (TT/TB)    // 75
#define COLSF (TB*VV)   // 100

// ws float layout:
//   [o*16]            channel sum   (line-spread, 64 ch, stride 16 floats) [0..1024)
//   [1024 + o*16]     channel sumsq                                        [1024..2048)
//   [2048+o] scale, [2112+o] shift, [2176+o] summed bias
//   byte 16384: A-hat fragments [s][nt][lane] short8 (6*64*16 = 6144 B)

static __device__ __forceinline__ short f2bf(float f){
    unsigned u = __float_as_uint(f);
    u += 0x7fff + ((u >> 16) & 1);
    return (short)(u >> 16);
}

__global__ void gcn_prep(const float* __restrict__ PA, const float* __restrict__ bc,
                         float* __restrict__ ws)
{
    __shared__ float inv[SS][VV];
    const int tid = threadIdx.x;   // 384 threads
    for (int i = tid; i < 2048; i += 384) ws[i] = 0.f;   // zero stats region
    if (tid < SS*VV){
        int s = tid/VV, w = tid%VV;
        float sum = 0.f;
        for (int v=0; v<VV; ++v){ float p = PA[s*VV*VV + v*VV + w]; sum = fmaf(p,p,sum); }
        inv[s][w] = 1.f/(sqrtf(sum)+1e-4f);
    }
    if (tid < CC) ws[2176 + tid] = bc[tid] + bc[CC+tid] + bc[2*CC+tid];
    __syncthreads();
    {   // fragment-ready normalized adjacency, zeros for v>=25 / w>=25
        int s = tid/128, rem = tid%128, nt = rem/64, lane = rem%64;
        int w = nt*16 + (lane&15), g = lane>>4;
        short8v vals;
        #pragma unroll
        for (int j=0;j<8;++j){
            int v = 8*g + j;
            float f = (v<VV && w<VV) ? PA[s*VV*VV + v*VV + w]*inv[s][w] : 0.f;
            vals[j] = f2bf(f);
        }
        *(short8v*)((char*)ws + 16384 + (size_t)((s*2+nt)*64 + lane)*16) = vals;
    }
}

__global__ __launch_bounds__(256,4) void gcn_main_kernel(
    const float* __restrict__ x, const float* __restrict__ Wc,
    const float* __restrict__ ws, float* __restrict__ yout)
{
    __shared__ short xs[256][40];    // rows=(c*4+t), bf16, v padded to 40
    __shared__ short zsT[112][68];   // rows=(t*25+w), cols=c ; pad 68 -> 34-dword stride

    const int tid = threadIdx.x;
    const int wv  = tid >> 6, lane = tid & 63;
    const int l15 = lane & 15, g = lane >> 4;
    const int n   = blockIdx.x / TBLK;
    const int t0  = (blockIdx.x % TBLK) * TB;

    // zero junk K-columns 25..31 (avoid NaN*0 in stage-A MFMA)
    xs[tid][25] = 0;
    *(int*)&xs[tid][26] = 0;
    *(int2*)&xs[tid][28] = make_int2(0,0);

    // stage x tile -> xs bf16 (coalesced float4 loads, b16 scatter writes)
    const float4* x4 = (const float4*)(x + (size_t)n*(CC*TT*VV) + (size_t)t0*VV);
    for (int i4 = tid; i4 < CC*COLSF/4; i4 += 256){    // 1600 float4
        int c = i4 / (COLSF/4);
        int j = i4 % (COLSF/4);
        float4 v4 = x4[c*(TT*VV/4) + j];
        float vals[4] = {v4.x, v4.y, v4.z, v4.w};
        int e = 4*j;
        #pragma unroll
        for (int k=0;k<4;++k){
            int ee = e+k;
            xs[c*TB + ee/VV][ee%VV] = f2bf(vals[k]);
        }
    }
    __syncthreads();

    // hoisted x A-fragments: wave owns xs rows [64*wv, 64*wv+64)
    short8v axf[4];
    #pragma unroll
    for (int mt=0; mt<4; ++mt)
        axf[mt] = *(const short8v*)&xs[64*wv + 16*mt + l15][8*g];

    const f32x4 zf = {0.f,0.f,0.f,0.f};
    f32x4 yacc[7];
    #pragma unroll
    for (int nt=0; nt<7; ++nt) yacc[nt] = zf;

    const short8v* wsfrag = (const short8v*)((const char*)ws + 16384);

    for (int s=0; s<SS; ++s){
        // per-s operand fragments (keeps steady-state register pressure low;
        // all of this is L2/L3-hot: ws frags 6 KB, Wc 48 KB shared by 4800 blocks)
        short8v afA0 = wsfrag[(s*2+0)*64 + lane];
        short8v afA1 = wsfrag[(s*2+1)*64 + lane];
        short8v wcf0, wcf1;
        {
            const float* wp = Wc + ((size_t)s*CC + (16*wv + l15))*CC + 8*g;
            float4 a0 = *(const float4*)(wp);
            float4 a1 = *(const float4*)(wp+4);
            float4 b0 = *(const float4*)(wp+32);
            float4 b1 = *(const float4*)(wp+36);
            wcf0[0]=f2bf(a0.x); wcf0[1]=f2bf(a0.y); wcf0[2]=f2bf(a0.z); wcf0[3]=f2bf(a0.w);
            wcf0[4]=f2bf(a1.x); wcf0[5]=f2bf(a1.y); wcf0[6]=f2bf(a1.z); wcf0[7]=f2bf(a1.w);
            wcf1[0]=f2bf(b0.x); wcf1[1]=f2bf(b0.y); wcf1[2]=f2bf(b0.z); wcf1[3]=f2bf(b0.w);
            wcf1[4]=f2bf(b1.x); wcf1[5]=f2bf(b1.y); wcf1[6]=f2bf(b1.z); wcf1[7]=f2bf(b1.w);
        }

        __syncthreads();   // prev stage-B reads of zsT complete

        // stage A: Z = X * A_hat[s]; scatter per mt (za transient: 8 regs)
        #pragma unroll
        for (int mt=0;mt<4;++mt){
            f32x4 za0 = __builtin_amdgcn_mfma_f32_16x16x32_bf16(axf[mt], afA0, zf, 0,0,0);
            f32x4 za1 = __builtin_amdgcn_mfma_f32_16x16x32_bf16(axf[mt], afA1, zf, 0,0,0);
            const int c = 16*wv + 4*mt + g;
            #pragma unroll
            for (int r=0;r<4;++r)
                zsT[r*VV + l15][c] = f2bf(za0[r]);          // w = l15 < 25 always
            if (l15 + 16 < VV){
                #pragma unroll
                for (int r=0;r<4;++r)
                    zsT[r*VV + 16 + l15][c] = f2bf(za1[r]); // w = 16+l15
            }
        }
        __syncthreads();   // zsT ready

        // stage B: yacc += Wc[s] * Z   (K = c = 64, 2 k-tiles)
        #pragma unroll
        for (int nt=0;nt<7;++nt){
            short8v bz0 = *(const short8v*)&zsT[nt*16 + l15][8*g];
            yacc[nt] = __builtin_amdgcn_mfma_f32_16x16x32_bf16(wcf0, bz0, yacc[nt], 0,0,0);
            short8v bz1 = *(const short8v*)&zsT[nt*16 + l15][32 + 8*g];
            yacc[nt] = __builtin_amdgcn_mfma_f32_16x16x32_bf16(wcf1, bz1, yacc[nt], 0,0,0);
        }
    }

    // epilogue: bias, store unnormalized y, channel stats (line-spread atomics)
    const float* wsb = ws + 2176;
    float s1[4] = {0,0,0,0}, s2[4] = {0,0,0,0};
    #pragma unroll
    for (int nt=0; nt<7; ++nt){
        int col = nt*16 + l15;
        if (col < COLSF){
            int t = col/VV, w = col%VV;
            #pragma unroll
            for (int r=0;r<4;++r){
                int o = 16*wv + 4*g + r;
                float v = yacc[nt][r] + wsb[o];
                yout[(((size_t)n*CC + o)*TT + t0 + t)*VV + w] = v;
                s1[r] += v;
                s2[r] = fmaf(v,v,s2[r]);
            }
        }
    }
    #pragma unroll
    for (int st=1; st<16; st<<=1){
        #pragma unroll
        for (int r=0;r<4;++r){
            s1[r] += __shfl_xor(s1[r], st);
            s2[r] += __shfl_xor(s2[r], st);
        }
    }
    if (l15 == 0){
        float* stats = (float*)ws;
        #pragma unroll
        for (int r=0;r<4;++r){
            int o = 16*wv + 4*g + r;
            atomicAdd(&stats[o*16], s1[r]);
            atomicAdd(&stats[1024 + o*16], s2[r]);
        }
    }
}

__global__ void gcn_finalize_kernel(const float* __restrict__ gamma,
                                    const float* __restrict__ beta,
                                    float* __restrict__ ws)
{
    const int o = threadIdx.x;
    if (o < CC) {
        const float cnt = (float)(NB * TT * VV);   // 480000
        const float mean = ws[o*16] / cnt;
        const float var  = ws[1024 + o*16] / cnt - mean * mean;
        const float sc   = gamma[o] * rsqrtf(var + 1e-5f);
        ws[2048 + o] = sc;
        ws[2112 + o] = beta[o] - mean * sc;
    }
}

__global__ __launch_bounds__(256) void gcn_bn_relu_kernel(
    const float* __restrict__ x, float* __restrict__ y,
    const float* __restrict__ ws)
{
    const int total4 = NB * CC * TT * VV / 4;   // 7,680,000
    const int per_c4 = TT * VV / 4;             // 1875
    for (int i = blockIdx.x * 256 + threadIdx.x; i < total4; i += gridDim.x * 256) {
        const int c = (i / per_c4) & (CC - 1);
        const float sc = ws[2048 + c];
        const float sh = ws[2112 + c];
        float4 yv = reinterpret_cast<float4*>(y)[i];
        float4 xv = reinterpret_cast<const float4*>(x)[i];
        float4 r;
        r.x = fmaxf(fmaf(yv.x, sc, sh) + xv.x, 0.f);
        r.y = fmaxf(fmaf(yv.y, sc, sh) + xv.y, 0.f);
        r.z = fmaxf(fmaf(yv.z, sc, sh) + xv.z, 0.f);
        r.w = fmaxf(fmaf(yv.w, sc, sh) + xv.w, 0.f);
        reinterpret_cast<float4*>(y)[i] = r;
    }
}

extern "C" void kernel_launch(void* const* d_in, const int* in_sizes, int n_in,
                              void* d_out, int out_size, void* d_ws, size_t ws_size,
                              hipStream_t stream)
{
    const float* x     = (const float*)d_in[0];
    const float* PA    = (const float*)d_in[1];
    const float* Wc    = (const float*)d_in[2];
    const float* bc    = (const float*)d_in[3];
    const float* gamma = (const float*)d_in[4];
    const float* beta  = (const float*)d_in[5];
    float* out = (float*)d_out;
    float* ws  = (float*)d_ws;

    gcn_prep<<<1, 384, 0, stream>>>(PA, bc, ws);
    gcn_main_kernel<<<NB * TBLK, 256, 0, stream>>>(x, Wc, ws, out);
    gcn_finalize_kernel<<<1, 64, 0, stream>>>(gamma, beta, ws);
    gcn_bn_relu_kernel<<<2048, 256, 0, stream>>>(x, out, ws);
}